// Round 2
// baseline (376.599 us; speedup 1.0000x reference)
//
#include <hip/hip_runtime.h>

// CrossWinAttention MI355X — round 2: bf16 MFMA pipeline.
//   K1 ln_proj_mfma : LN(f32 stats) -> bf16 Y tile (LDS, swizzled) x W^T (LDS bf16,
//                     swizzled) via mfma_f32_16x16x32_bf16; Z^T form => vectorized stores.
//   K2 attn_mfma    : per (b,m,l): K bf16 LDS [t][dh], V^T bf16 LDS [dh][t] (swizzled);
//                     QK^T (1 MFMA/tile, K=Dh=32), single-pass exp (logits tiny), P->LDS
//                     (swizzled) -> PV MFMAs; normalize O by lane-local row sums; in-place.
//   K3 out_proj     : n-sum first (mean commutes with proj), fp32 VALU 128x128 proj.
// Workspace: ALWAYS bf16 (3 x 32MB = 96MB).
// MFMA layout assumption (single point of failure, flip if incorrect):
//   A[l&15][(l>>4)*8+i] ; B[(l>>4)*8+i][l&15] ; D reg j -> [(l>>4)*4+j][l&15]

typedef unsigned short u16;
typedef short bf16x8 __attribute__((ext_vector_type(8)));
typedef float f32x4 __attribute__((ext_vector_type(4)));

__device__ __forceinline__ float bf2f(u16 u) {
  union { unsigned int i; float f; } v; v.i = ((unsigned int)u) << 16; return v.f;
}
__device__ __forceinline__ u16 f2bf(float f) {
  union { float f; unsigned int i; } v; v.f = f;
  unsigned int x = v.i;
  return (u16)((x + 0x7fffu + ((x >> 16) & 1u)) >> 16);  // RNE
}

// ---------------------------------------------------------------------------
// Kernel 1: fused LN + projection, bf16 MFMA. grid (256, 3), 256 thr, 8 chunks.
// Per chunk: 64 tokens. Wave w owns token strip w*16..w*16+15 (cols of Z^T).
// ---------------------------------------------------------------------------
__global__ __launch_bounds__(256) void ln_proj_mfma(
    const float* __restrict__ xq, const float* __restrict__ xk, const float* __restrict__ xv,
    const float* __restrict__ g_q, const float* __restrict__ b_q,
    const float* __restrict__ g_k, const float* __restrict__ b_k,
    const float* __restrict__ g_v, const float* __restrict__ b_v,
    const float* __restrict__ wq, const float* __restrict__ bq,
    const float* __restrict__ wk, const float* __restrict__ bk,
    const float* __restrict__ wv, const float* __restrict__ bv,
    u16* __restrict__ Qp, u16* __restrict__ Kp, u16* __restrict__ Vp)
{
  __shared__ u16 Wt_s[128 * 128];   // [c][d], d-contiguous, swizzled ^((c&7)<<3)  (32 KB)
  __shared__ u16 Y_s[64 * 128];     // [tok][d], d-contiguous, swizzled ^((tok&7)<<3) (16 KB)

  const float *xp, *gp, *bp, *Wp, *biasp;
  u16* outp;
  if (blockIdx.y == 0)      { xp = xq; gp = g_q; bp = b_q; Wp = wq; biasp = bq; outp = Qp; }
  else if (blockIdx.y == 1) { xp = xk; gp = g_k; bp = b_k; Wp = wk; biasp = bk; outp = Kp; }
  else                      { xp = xv; gp = g_v; bp = b_v; Wp = wv; biasp = bv; outp = Vp; }

  const int tid = threadIdx.x;

  // ---- stage W transposed: Wt_s[c][d] = bf16(W[d][c]) ----
#pragma unroll
  for (int it = 0; it < 16; ++it) {
    int f = it * 256 + tid;
    int d = f >> 5, c4 = (f & 31) * 4;
    float4 w4 = *(const float4*)(Wp + d * 128 + c4);
    Wt_s[(c4 + 0) * 128 + (d ^ (((c4 + 0) & 7) << 3))] = f2bf(w4.x);
    Wt_s[(c4 + 1) * 128 + (d ^ (((c4 + 1) & 7) << 3))] = f2bf(w4.y);
    Wt_s[(c4 + 2) * 128 + (d ^ (((c4 + 2) & 7) << 3))] = f2bf(w4.z);
    Wt_s[(c4 + 3) * 128 + (d ^ (((c4 + 3) & 7) << 3))] = f2bf(w4.w);
  }

  const int lane = tid & 63, wv_ = tid >> 6;
  // LN mapping: 32-lane groups, one token per group per pass
  const int l32 = lane & 31, hi = lane >> 5;
  const int d4 = l32 * 4;
  const float4 g4  = *(const float4*)(gp + d4);
  const float4 bb4 = *(const float4*)(bp + d4);
  // MFMA lane mapping
  const int c0 = lane & 15, g = lane >> 4;

  __syncthreads();

  for (int ci = 0; ci < 8; ++ci) {
    const int tile = blockIdx.x * 8 + ci;
    const int tok0 = tile * 64;
    // ---- LN: 8 passes x 8 tokens -> Y_s bf16 ----
#pragma unroll
    for (int p = 0; p < 8; ++p) {
      int tt = p * 8 + wv_ * 2 + hi;
      int tok = tok0 + tt;
      int t = tok & 255, bl = tok >> 8;
      int l = bl & 255, bi = bl >> 8;
      int xx = l >> 4, yy = l & 15;
      int n = t >> 6, w1 = (t >> 3) & 7, w2 = t & 7;
      int row = (((((bi * 4 + n) * 16 + xx) * 16 + yy) * 8 + w1) * 8 + w2) * 128;
      float4 x4 = *(const float4*)(xp + row + d4);
      float s1 = x4.x + x4.y + x4.z + x4.w;
      float s2 = x4.x * x4.x + x4.y * x4.y + x4.z * x4.z + x4.w * x4.w;
#pragma unroll
      for (int off = 16; off >= 1; off >>= 1) {
        s1 += __shfl_xor(s1, off);
        s2 += __shfl_xor(s2, off);
      }
      float mu = s1 * (1.0f / 128.0f);
      float var = s2 * (1.0f / 128.0f) - mu * mu;
      float rs = rsqrtf(var + 1e-5f);
      ushort4 yv;
      yv.x = f2bf((x4.x - mu) * rs * g4.x + bb4.x);
      yv.y = f2bf((x4.y - mu) * rs * g4.y + bb4.y);
      yv.z = f2bf((x4.z - mu) * rs * g4.z + bb4.z);
      yv.w = f2bf((x4.w - mu) * rs * g4.w + bb4.w);
      *(ushort4*)&Y_s[tt * 128 + (d4 ^ ((tt & 7) << 3))] = yv;
    }
    __syncthreads();
    // ---- Z^T = W^T . Y^T : wave = token strip, loop over 8 channel tiles ----
    bf16x8 bfr[4];
#pragma unroll
    for (int ks = 0; ks < 4; ++ks)
      bfr[ks] = *(const bf16x8*)&Y_s[(wv_ * 16 + c0) * 128 + ((ks * 32 + g * 8) ^ ((c0 & 7) << 3))];
#pragma unroll
    for (int ct = 0; ct < 8; ++ct) {
      f32x4 acc = {0.f, 0.f, 0.f, 0.f};
#pragma unroll
      for (int ks = 0; ks < 4; ++ks) {
        bf16x8 afr = *(const bf16x8*)&Wt_s[(ct * 16 + c0) * 128 + ((ks * 32 + g * 8) ^ ((c0 & 7) << 3))];
        acc = __builtin_amdgcn_mfma_f32_16x16x32_bf16(afr, bfr[ks], acc, 0, 0, 0);
      }
      int cb = ct * 16 + g * 4;
      float4 b4 = *(const float4*)(biasp + cb);
      ushort4 zv;
      zv.x = f2bf(acc[0] + b4.x);
      zv.y = f2bf(acc[1] + b4.y);
      zv.z = f2bf(acc[2] + b4.z);
      zv.w = f2bf(acc[3] + b4.w);
      *(ushort4*)(outp + (tok0 + wv_ * 16 + c0) * 128 + cb) = zv;
    }
    __syncthreads();
  }
}

// ---------------------------------------------------------------------------
// Kernel 2: attention per (b,m,l), bf16 MFMA. 2048 blocks x 256 thr (4 waves).
// Wave w: q strips w*4..w*4+3 (16 rows each). In-place O -> Qp.
// ---------------------------------------------------------------------------
__global__ __launch_bounds__(256) void attn_mfma(
    u16* __restrict__ Qp, const u16* __restrict__ Kp, const u16* __restrict__ Vp,
    const float* __restrict__ temperature)
{
  __shared__ u16 K_s[256 * 32];        // [t][dh]   16 KB, no swizzle (reads are even)
  __shared__ u16 Vt_s[32 * 256];       // [dh][t]   16 KB, swizzled ^((dh&7)<<3)
  __shared__ u16 P_s[4][16 * 256];     // per-wave [qrow][k] 8 KB, swizzled ^((row&7)<<3)

  const int tid = threadIdx.x;
  const int bid = blockIdx.x;
  const int l = bid & 255, m = (bid >> 8) & 3, b = bid >> 10;
  const float scale = 0.17677669529663689f / temperature[b];   // 32^-0.5 / temp
  const int base = (b * 256 + l) * 32768 + m * 32;             // + t*128 + dh

  // ---- stage K: straight bf16 copy ----
#pragma unroll
  for (int r = 0; r < 8; ++r) {
    int f = r * 256 + tid, t = f >> 3, c4 = (f & 7) * 4;
    *(ushort4*)&K_s[t * 32 + c4] = *(const ushort4*)(Kp + base + t * 128 + c4);
  }
  // ---- stage V transposed ----
  {
    const int dh = tid & 31, kq = tid >> 5;
#pragma unroll
    for (int jj = 0; jj < 4; ++jj) {
      bf16x8 v;
#pragma unroll
      for (int e = 0; e < 8; ++e)
        v[e] = (short)Vp[base + (kq * 32 + jj * 8 + e) * 128 + dh];
      *(bf16x8*)&Vt_s[dh * 256 + ((kq * 32 + jj * 8) ^ ((dh & 7) << 3))] = v;
    }
  }
  __syncthreads();

  const int lane = tid & 63, wv_ = tid >> 6;
  const int c0 = lane & 15, g = lane >> 4;
  u16* Pw = P_s[wv_];
  const f32x4 zero = {0.f, 0.f, 0.f, 0.f};

  for (int si = 0; si < 4; ++si) {
    const int qs = wv_ * 4 + si;
    // Q fragment straight from global (K=Dh=32: one k-step)
    bf16x8 qf = *(const bf16x8*)(Qp + base + (qs * 16 + c0) * 128 + g * 8);
    // ---- QK^T: 16 tiles ----
    f32x4 s[16];
#pragma unroll
    for (int kt = 0; kt < 16; ++kt) {
      bf16x8 kf = *(const bf16x8*)&K_s[(kt * 16 + c0) * 32 + g * 8];
      s[kt] = __builtin_amdgcn_mfma_f32_16x16x32_bf16(qf, kf, zero, 0, 0, 0);
    }
    // ---- exp + row partial sums + P -> LDS ----
    float p0 = 0.f, p1 = 0.f, p2 = 0.f, p3 = 0.f;
#pragma unroll
    for (int kt = 0; kt < 16; ++kt) {
      float e0 = __expf(s[kt][0] * scale);
      float e1 = __expf(s[kt][1] * scale);
      float e2 = __expf(s[kt][2] * scale);
      float e3 = __expf(s[kt][3] * scale);
      p0 += e0; p1 += e1; p2 += e2; p3 += e3;
      int col = kt * 16 + c0;
      int r0 = g * 4;
      Pw[(r0 + 0) * 256 + (col ^ (((r0 + 0) & 7) << 3))] = f2bf(e0);
      Pw[(r0 + 1) * 256 + (col ^ (((r0 + 1) & 7) << 3))] = f2bf(e1);
      Pw[(r0 + 2) * 256 + (col ^ (((r0 + 2) & 7) << 3))] = f2bf(e2);
      Pw[(r0 + 3) * 256 + (col ^ (((r0 + 3) & 7) << 3))] = f2bf(e3);
    }
#pragma unroll
    for (int off = 1; off <= 8; off <<= 1) {
      p0 += __shfl_xor(p0, off);
      p1 += __shfl_xor(p1, off);
      p2 += __shfl_xor(p2, off);
      p3 += __shfl_xor(p3, off);
    }
    float inv0 = 1.0f / p0, inv1 = 1.0f / p1, inv2 = 1.0f / p2, inv3 = 1.0f / p3;
    // ---- PV: O = P.V, accumulate over 8 k-chunks, 2 dh tiles ----
    f32x4 o0 = zero, o1 = zero;
#pragma unroll
    for (int kc = 0; kc < 8; ++kc) {
      int off8 = (kc * 32 + g * 8) ^ ((c0 & 7) << 3);
      bf16x8 af = *(const bf16x8*)&Pw[c0 * 256 + off8];
      bf16x8 v0 = *(const bf16x8*)&Vt_s[c0 * 256 + off8];
      bf16x8 v1 = *(const bf16x8*)&Vt_s[(16 + c0) * 256 + off8];
      o0 = __builtin_amdgcn_mfma_f32_16x16x32_bf16(af, v0, o0, 0, 0, 0);
      o1 = __builtin_amdgcn_mfma_f32_16x16x32_bf16(af, v1, o1, 0, 0, 0);
    }
    // ---- normalize + in-place store (rows match lane-local sums) ----
    int qrow = qs * 16 + g * 4;
    Qp[base + (qrow + 0) * 128 + c0]      = f2bf(o0[0] * inv0);
    Qp[base + (qrow + 1) * 128 + c0]      = f2bf(o0[1] * inv1);
    Qp[base + (qrow + 2) * 128 + c0]      = f2bf(o0[2] * inv2);
    Qp[base + (qrow + 3) * 128 + c0]      = f2bf(o0[3] * inv3);
    Qp[base + (qrow + 0) * 128 + 16 + c0] = f2bf(o1[0] * inv0);
    Qp[base + (qrow + 1) * 128 + 16 + c0] = f2bf(o1[1] * inv1);
    Qp[base + (qrow + 2) * 128 + 16 + c0] = f2bf(o1[2] * inv2);
    Qp[base + (qrow + 3) * 128 + 16 + c0] = f2bf(o1[3] * inv3);
  }
}

// ---------------------------------------------------------------------------
// Kernel 3: out projection + mean over n + bias + skip (fp32 VALU).
// ---------------------------------------------------------------------------
__global__ __launch_bounds__(256) void out_proj_kernel(
    const u16* __restrict__ Ap, const float* __restrict__ wp, const float* __restrict__ bpr,
    const float* __restrict__ skip, float* __restrict__ out, int chunks_per_block)
{
  __shared__ u16   WP_s[128 * 128];  // 32 KB bf16
  __shared__ float a_s[128][8];      // n-summed activations
  const int tid = threadIdx.x;
#pragma unroll
  for (int r = 0; r < 16; ++r) {
    int f4 = r * 256 + tid;
    float4 w4 = *(const float4*)(wp + f4 * 4);
    ushort4 u; u.x = f2bf(w4.x); u.y = f2bf(w4.y); u.z = f2bf(w4.z); u.w = f2bf(w4.w);
    *(ushort4*)&WP_s[f4 * 4] = u;
  }
  const int pp = tid >> 7, c = tid & 127;
  const float bias_c = bpr[c];
  const int tj = tid & 7, cb = (tid >> 3) * 4;
  __syncthreads();

  for (int ci = 0; ci < chunks_per_block; ++ci) {
    const int ch = blockIdx.x * chunks_per_block + ci;
    {   // stage n-sum
      int o = ch * 8 + tj;
      int w = o & 63, bl = o >> 6;
      int l = bl & 255, b = bl >> 8;
      int rb = (b * 256 + l) * 32768;
      float4 sum = make_float4(0.f, 0.f, 0.f, 0.f);
#pragma unroll
      for (int n = 0; n < 4; ++n) {
        int t = n * 64 + w;
        ushort4 a4 = *(const ushort4*)(Ap + rb + t * 128 + cb);
        sum.x += bf2f(a4.x); sum.y += bf2f(a4.y);
        sum.z += bf2f(a4.z); sum.w += bf2f(a4.w);
      }
      a_s[cb + 0][tj] = sum.x; a_s[cb + 1][tj] = sum.y;
      a_s[cb + 2][tj] = sum.z; a_s[cb + 3][tj] = sum.w;
    }
    __syncthreads();
    {
      float a0 = 0, a1 = 0, a2 = 0, a3 = 0;
#pragma unroll 4
      for (int cp = 0; cp < 128; ++cp) {
        float4 av = *(const float4*)&a_s[cp][pp * 4];   // broadcast
        float w = bf2f(WP_s[cp * 128 + c]);
        a0 += av.x * w; a1 += av.y * w; a2 += av.z * w; a3 += av.w * w;
      }
      int ob = (ch * 8 + pp * 4) * 128 + c;
      out[ob]       = 0.25f * a0 + bias_c + skip[ob];
      out[ob + 128] = 0.25f * a1 + bias_c + skip[ob + 128];
      out[ob + 256] = 0.25f * a2 + bias_c + skip[ob + 256];
      out[ob + 384] = 0.25f * a3 + bias_c + skip[ob + 384];
    }
    __syncthreads();
  }
}

// ---------------------------------------------------------------------------
extern "C" void kernel_launch(void* const* d_in, const int* in_sizes, int n_in,
                              void* d_out, int out_size, void* d_ws, size_t ws_size,
                              hipStream_t stream)
{
  (void)in_sizes; (void)n_in; (void)out_size; (void)ws_size;
  const float* q    = (const float*)d_in[0];
  const float* k    = (const float*)d_in[1];
  const float* v    = (const float*)d_in[2];
  const float* skip = (const float*)d_in[3];
  const float* temp = (const float*)d_in[4];
  const float* gq   = (const float*)d_in[5];
  const float* bq_l = (const float*)d_in[6];
  const float* gk   = (const float*)d_in[7];
  const float* bk_l = (const float*)d_in[8];
  const float* gv   = (const float*)d_in[9];
  const float* bv_l = (const float*)d_in[10];
  const float* wq   = (const float*)d_in[11];
  const float* bq   = (const float*)d_in[12];
  const float* wk   = (const float*)d_in[13];
  const float* bk   = (const float*)d_in[14];
  const float* wv   = (const float*)d_in[15];
  const float* bv   = (const float*)d_in[16];
  const float* wp   = (const float*)d_in[17];
  const float* bp   = (const float*)d_in[18];
  float* out = (float*)d_out;

  const size_t S = (size_t)2 * 256 * 256 * 128;   // 16,777,216 elements per tensor
  u16* Qp = (u16*)d_ws;
  u16* Kp = Qp + S;
  u16* Vp = Kp + S;

  ln_proj_mfma<<<dim3(256, 3), 256, 0, stream>>>(
      q, k, v, gq, bq_l, gk, bk_l, gv, bv_l,
      wq, bq, wk, bk, wv, bv, Qp, Kp, Vp);
  attn_mfma<<<dim3(2048), 256, 0, stream>>>(Qp, Kp, Vp, temp);
  out_proj_kernel<<<dim3(512), 256, 0, stream>>>(Qp, wp, bp, skip, out, 8);
}

// Round 5
// 348.835 us; speedup vs baseline: 1.0796x; 1.0796x over previous
//
#include <hip/hip_runtime.h>

// CrossWinAttention MI355X — round 3 kernel, resubmit #2 (rounds 3+4 benches never ran:
// GPU acquisition timeouts). Desk-audited this round; no changes.
// K1 ln_proj_mfma: LN folded into GEMM: z = rs*(x@(g.W) - mu*S) + (bias + b_ln@W).
//    No Y_s, no in-loop barriers; W' staged u32-packed, stride 136 + (c&15)<<3 swizzle.
//    V output stored TRANSPOSED [head][dh][t] for K2.
// K2 attn_mfma: K_s linear, Vt_s staged vectorized from pre-transposed VpT,
//    P chunked to 64 cols (LDS 40KB -> 4 blocks/CU). Verified MFMA mappings unchanged.
// K3 out_proj_mfma: n-sum first (mean commutes), bf16 MFMA, 0.25 folded into W.
// Workspace: bf16, Qp | Kp | VpT = 96 MB.

typedef unsigned short u16;
typedef unsigned int u32;
typedef short bf16x8 __attribute__((ext_vector_type(8)));
typedef float f32x4 __attribute__((ext_vector_type(4)));

__device__ __forceinline__ float bf2f(u16 u) {
  union { unsigned int i; float f; } v; v.i = ((unsigned int)u) << 16; return v.f;
}
__device__ __forceinline__ u16 f2bf(float f) {
  union { float f; unsigned int i; } v; v.f = f;
  unsigned int x = v.i;
  return (u16)((x + 0x7fffu + ((x >> 16) & 1u)) >> 16);  // RNE
}

// ---------------------------------------------------------------------------
// Kernel 1: LN algebraically folded into bf16 MFMA projection.
// grid (256, 3); 4 rounds x 2-tile batch; wave = 16-token strip; no loop barriers.
// ---------------------------------------------------------------------------
__global__ __launch_bounds__(256) void ln_proj_mfma(
    const float* __restrict__ xq, const float* __restrict__ xk, const float* __restrict__ xv,
    const float* __restrict__ g_q, const float* __restrict__ b_q,
    const float* __restrict__ g_k, const float* __restrict__ b_k,
    const float* __restrict__ g_v, const float* __restrict__ b_v,
    const float* __restrict__ wq, const float* __restrict__ bq,
    const float* __restrict__ wk, const float* __restrict__ bk,
    const float* __restrict__ wv, const float* __restrict__ bv,
    u16* __restrict__ Qp, u16* __restrict__ Kp, u16* __restrict__ VpT)
{
  __shared__ u16  Wt_s[128 * 136];   // [c][d] = bf16(g_d*W[d][c]); swz d ^ ((c&15)<<3); pad 136
  __shared__ float S_s[128];         // S_c  = sum_d g_d W[d][c]   (f32)
  __shared__ float B2_s[128];        // B2_c = bias_c + sum_d b_d W[d][c]

  const float *xp, *gp, *bp, *Wp, *biasp;
  u16* outp;
  if (blockIdx.y == 0)      { xp = xq; gp = g_q; bp = b_q; Wp = wq; biasp = bq; outp = Qp; }
  else if (blockIdx.y == 1) { xp = xk; gp = g_k; bp = b_k; Wp = wk; biasp = bk; outp = Kp; }
  else                      { xp = xv; gp = g_v; bp = b_v; Wp = wv; biasp = bv; outp = VpT; }

  const int tid = threadIdx.x;

  // ---- stage W' transposed, u32-packed (each lane writes a distinct dword) ----
#pragma unroll
  for (int it = 0; it < 32; ++it) {
    int f = it * 256 + tid;               // u32-chunk id in [0, 8192)
    int c = f & 127, d0 = (f >> 7) * 2;
    float w0 = Wp[d0 * 128 + c] * gp[d0];
    float w1 = Wp[(d0 + 1) * 128 + c] * gp[d0 + 1];
    u32 pk = (u32)f2bf(w0) | ((u32)f2bf(w1) << 16);
    *(u32*)&Wt_s[c * 136 + (d0 ^ ((c & 15) << 3))] = pk;
  }
  // ---- S_c (threads 0..127) and B2_c (threads 128..255), coalesced over c ----
  {
    int c = tid & 127;
    float accv = 0.f;
#pragma unroll 4
    for (int d = 0; d < 128; ++d) {
      float coef = (tid < 128) ? gp[d] : bp[d];
      accv += coef * Wp[d * 128 + c];
    }
    if (tid < 128) S_s[c] = accv;
    else           B2_s[c] = accv + biasp[c];
  }
  __syncthreads();   // the only barrier

  const int lane = tid & 63, wv_ = tid >> 6;
  const int c0 = lane & 15, g = lane >> 4;

  for (int rnd = 0; rnd < 4; ++rnd) {
    const int tilebase = (blockIdx.x * 4 + rnd) * 2;
    bf16x8 xf[2][4];
    float mu[2], rsv[2];
    int tokv[2];
#pragma unroll
    for (int t = 0; t < 2; ++t) {
      int tok = (tilebase + t) * 64 + wv_ * 16 + c0;
      tokv[t] = tok;
      int tt = tok & 255, bl = tok >> 8;
      int l = bl & 255, bi = bl >> 8;
      int xx = l >> 4, yy = l & 15;
      int n = tt >> 6, w1 = (tt >> 3) & 7, w2 = tt & 7;
      int row = (((((bi * 4 + n) * 16 + xx) * 16 + yy) * 8 + w1) * 8 + w2) * 128;
      float s1 = 0.f, s2 = 0.f;
#pragma unroll
      for (int ks = 0; ks < 4; ++ks) {
        float4 lo = *(const float4*)(xp + row + ks * 32 + g * 8);
        float4 hi = *(const float4*)(xp + row + ks * 32 + g * 8 + 4);
        s1 += lo.x + lo.y + lo.z + lo.w + hi.x + hi.y + hi.z + hi.w;
        s2 += lo.x * lo.x + lo.y * lo.y + lo.z * lo.z + lo.w * lo.w
            + hi.x * hi.x + hi.y * hi.y + hi.z * hi.z + hi.w * hi.w;
        bf16x8 xv;
        xv[0] = (short)f2bf(lo.x); xv[1] = (short)f2bf(lo.y);
        xv[2] = (short)f2bf(lo.z); xv[3] = (short)f2bf(lo.w);
        xv[4] = (short)f2bf(hi.x); xv[5] = (short)f2bf(hi.y);
        xv[6] = (short)f2bf(hi.z); xv[7] = (short)f2bf(hi.w);
        xf[t][ks] = xv;
      }
      s1 += __shfl_xor(s1, 16); s2 += __shfl_xor(s2, 16);
      s1 += __shfl_xor(s1, 32); s2 += __shfl_xor(s2, 32);
      float m = s1 * (1.0f / 128.0f);
      float var = s2 * (1.0f / 128.0f) - m * m;
      mu[t] = m;
      rsv[t] = rsqrtf(var + 1e-5f);
    }
#pragma unroll
    for (int ct = 0; ct < 8; ++ct) {
      const int cb = ct * 16 + g * 4;
      float4 S4 = *(const float4*)&S_s[cb];
      float4 B4 = *(const float4*)&B2_s[cb];
      bf16x8 wf[4];
#pragma unroll
      for (int ks = 0; ks < 4; ++ks)
        wf[ks] = *(const bf16x8*)&Wt_s[(ct * 16 + c0) * 136 + ((ks * 32 + g * 8) ^ (c0 << 3))];
#pragma unroll
      for (int t = 0; t < 2; ++t) {
        f32x4 acc = {0.f, 0.f, 0.f, 0.f};
#pragma unroll
        for (int ks = 0; ks < 4; ++ks)
          acc = __builtin_amdgcn_mfma_f32_16x16x32_bf16(wf[ks], xf[t][ks], acc, 0, 0, 0);
        float z0 = rsv[t] * (acc[0] - mu[t] * S4.x) + B4.x;
        float z1 = rsv[t] * (acc[1] - mu[t] * S4.y) + B4.y;
        float z2 = rsv[t] * (acc[2] - mu[t] * S4.z) + B4.z;
        float z3 = rsv[t] * (acc[3] - mu[t] * S4.w) + B4.w;
        if (blockIdx.y == 2) {
          // V stored transposed: [head][dh][t], head = bl*4 + m
          int head = (tokv[t] >> 8) * 4 + (cb >> 5);
          int dh0 = cb & 31, tcol = tokv[t] & 255;
          outp[(head * 32 + dh0 + 0) * 256 + tcol] = f2bf(z0);
          outp[(head * 32 + dh0 + 1) * 256 + tcol] = f2bf(z1);
          outp[(head * 32 + dh0 + 2) * 256 + tcol] = f2bf(z2);
          outp[(head * 32 + dh0 + 3) * 256 + tcol] = f2bf(z3);
        } else {
          ushort4 zv;
          zv.x = f2bf(z0); zv.y = f2bf(z1); zv.z = f2bf(z2); zv.w = f2bf(z3);
          *(ushort4*)(outp + tokv[t] * 128 + cb) = zv;
        }
      }
    }
  }
}

// ---------------------------------------------------------------------------
// Kernel 2: attention per (b,m,l). 2048 blocks x 256 thr (4 waves).
// LDS 40KB (K 16 + Vt 16 + P 8) -> 4 blocks/CU. P chunked to 64 k-cols.
// ---------------------------------------------------------------------------
__global__ __launch_bounds__(256) void attn_mfma(
    u16* __restrict__ Qp, const u16* __restrict__ Kp, const u16* __restrict__ VpT,
    const float* __restrict__ temperature)
{
  __shared__ u16 K_s[256 * 32];        // [t][dh] linear (b128 reads are uniform-spread)
  __shared__ u16 Vt_s[32 * 256];       // [dh][t], swz t ^ ((dh&7)<<3)
  __shared__ u16 P_s[4][16 * 64];      // per-wave [qrow][k-chunk 64], swz ^((row&7)<<3)

  const int tid = threadIdx.x;
  const int bid = blockIdx.x;
  const int l = bid & 255, m = (bid >> 8) & 3, b = bid >> 10;
  const float scale = 0.17677669529663689f / temperature[b];   // 32^-0.5 / temp
  const int base = (b * 256 + l) * 32768 + m * 32;             // Qp/Kp: + t*128 + dh
  const int head = (b * 256 + l) * 4 + m;

#pragma unroll
  for (int r = 0; r < 8; ++r) {        // K: vectorized copy
    int f = r * 256 + tid, t = f >> 3, c4 = (f & 7) * 4;
    *(ushort4*)&K_s[t * 32 + c4] = *(const ushort4*)(Kp + base + t * 128 + c4);
  }
#pragma unroll
  for (int r = 0; r < 8; ++r) {        // V^T: vectorized copy from pre-transposed global
    int f = r * 256 + tid, dh = f >> 6, c4 = (f & 63) * 4;
    ushort4 vv = *(const ushort4*)(VpT + (head * 32 + dh) * 256 + c4);
    *(ushort4*)&Vt_s[dh * 256 + (c4 ^ ((dh & 7) << 3))] = vv;
  }
  __syncthreads();

  const int lane = tid & 63, wv_ = tid >> 6;
  const int c0 = lane & 15, g = lane >> 4;
  u16* Pw = P_s[wv_];
  const f32x4 zero = {0.f, 0.f, 0.f, 0.f};

  for (int si = 0; si < 4; ++si) {
    const int qs = wv_ * 4 + si;
    bf16x8 qf = *(const bf16x8*)(Qp + base + (qs * 16 + c0) * 128 + g * 8);
    float p0 = 0.f, p1 = 0.f, p2 = 0.f, p3 = 0.f;
    f32x4 o0 = zero, o1 = zero;
    const int r0 = g * 4;
#pragma unroll 1
    for (int cc = 0; cc < 4; ++cc) {
      f32x4 s[4];
#pragma unroll
      for (int kt = 0; kt < 4; ++kt) {
        bf16x8 kf = *(const bf16x8*)&K_s[((cc * 4 + kt) * 16 + c0) * 32 + g * 8];
        s[kt] = __builtin_amdgcn_mfma_f32_16x16x32_bf16(qf, kf, zero, 0, 0, 0);
      }
#pragma unroll
      for (int kt = 0; kt < 4; ++kt) {
        float e0 = __expf(s[kt][0] * scale);
        float e1 = __expf(s[kt][1] * scale);
        float e2 = __expf(s[kt][2] * scale);
        float e3 = __expf(s[kt][3] * scale);
        p0 += e0; p1 += e1; p2 += e2; p3 += e3;
        int col = kt * 16 + c0;
        Pw[(r0 + 0) * 64 + (col ^ (((r0 + 0) & 7) << 3))] = f2bf(e0);
        Pw[(r0 + 1) * 64 + (col ^ (((r0 + 1) & 7) << 3))] = f2bf(e1);
        Pw[(r0 + 2) * 64 + (col ^ (((r0 + 2) & 7) << 3))] = f2bf(e2);
        Pw[(r0 + 3) * 64 + (col ^ (((r0 + 3) & 7) << 3))] = f2bf(e3);
      }
#pragma unroll
      for (int kc = 0; kc < 2; ++kc) {
        bf16x8 af = *(const bf16x8*)&Pw[c0 * 64 + ((kc * 32 + g * 8) ^ ((c0 & 7) << 3))];
        int Kg = cc * 64 + kc * 32 + g * 8;
        bf16x8 v0 = *(const bf16x8*)&Vt_s[c0 * 256 + (Kg ^ ((c0 & 7) << 3))];
        bf16x8 v1 = *(const bf16x8*)&Vt_s[(16 + c0) * 256 + (Kg ^ ((c0 & 7) << 3))];
        o0 = __builtin_amdgcn_mfma_f32_16x16x32_bf16(af, v0, o0, 0, 0, 0);
        o1 = __builtin_amdgcn_mfma_f32_16x16x32_bf16(af, v1, o1, 0, 0, 0);
      }
    }
#pragma unroll
    for (int off = 1; off <= 8; off <<= 1) {
      p0 += __shfl_xor(p0, off);
      p1 += __shfl_xor(p1, off);
      p2 += __shfl_xor(p2, off);
      p3 += __shfl_xor(p3, off);
    }
    float inv0 = 1.0f / p0, inv1 = 1.0f / p1, inv2 = 1.0f / p2, inv3 = 1.0f / p3;
    int qrow = qs * 16 + g * 4;
    Qp[base + (qrow + 0) * 128 + c0]      = f2bf(o0[0] * inv0);
    Qp[base + (qrow + 1) * 128 + c0]      = f2bf(o0[1] * inv1);
    Qp[base + (qrow + 2) * 128 + c0]      = f2bf(o0[2] * inv2);
    Qp[base + (qrow + 3) * 128 + c0]      = f2bf(o0[3] * inv3);
    Qp[base + (qrow + 0) * 128 + 16 + c0] = f2bf(o1[0] * inv0);
    Qp[base + (qrow + 1) * 128 + 16 + c0] = f2bf(o1[1] * inv1);
    Qp[base + (qrow + 2) * 128 + 16 + c0] = f2bf(o1[2] * inv2);
    Qp[base + (qrow + 3) * 128 + 16 + c0] = f2bf(o1[3] * inv3);
  }
}

// ---------------------------------------------------------------------------
// Kernel 3: out projection (MFMA) + mean over n + bias + skip. 512 blocks = 512 (b,l)
// tiles of 64 output tokens. 0.25 (mean) folded into staged W.
// ---------------------------------------------------------------------------
__global__ __launch_bounds__(256) void out_proj_mfma(
    const u16* __restrict__ Ap, const float* __restrict__ wp, const float* __restrict__ bpr,
    const float* __restrict__ skip, float* __restrict__ out)
{
  __shared__ u16 WpT_s[128 * 136];   // [dout][cin] = bf16(0.25*wp[cin][dout])
  const int tid = threadIdx.x;
#pragma unroll
  for (int it = 0; it < 32; ++it) {
    int f = it * 256 + tid;
    int c = f & 127, d0 = (f >> 7) * 2;     // c = dout, d0 = cin pair
    float w0 = wp[d0 * 128 + c] * 0.25f;
    float w1 = wp[(d0 + 1) * 128 + c] * 0.25f;
    u32 pk = (u32)f2bf(w0) | ((u32)f2bf(w1) << 16);
    *(u32*)&WpT_s[c * 136 + (d0 ^ ((c & 15) << 3))] = pk;
  }
  __syncthreads();

  const int lane = tid & 63, wv_ = tid >> 6;
  const int c0 = lane & 15, g = lane >> 4;
  const int bl = blockIdx.x;                 // one (b,l) per block
  const int w = wv_ * 16 + c0;
  const int otok = bl * 64 + w;

  bf16x8 bfr[4];
#pragma unroll
  for (int ks = 0; ks < 4; ++ks) {
    float acc8[8] = {0.f, 0.f, 0.f, 0.f, 0.f, 0.f, 0.f, 0.f};
#pragma unroll
    for (int n = 0; n < 4; ++n) {
      bf16x8 a = *(const bf16x8*)(Ap + (bl * 256 + n * 64 + w) * 128 + ks * 32 + g * 8);
#pragma unroll
      for (int e = 0; e < 8; ++e) acc8[e] += bf2f((u16)a[e]);
    }
    bf16x8 r;
#pragma unroll
    for (int e = 0; e < 8; ++e) r[e] = (short)f2bf(acc8[e]);
    bfr[ks] = r;
  }
#pragma unroll
  for (int ct = 0; ct < 8; ++ct) {
    f32x4 acc = {0.f, 0.f, 0.f, 0.f};
#pragma unroll
    for (int ks = 0; ks < 4; ++ks) {
      bf16x8 wf = *(const bf16x8*)&WpT_s[(ct * 16 + c0) * 136 + ((ks * 32 + g * 8) ^ (c0 << 3))];
      acc = __builtin_amdgcn_mfma_f32_16x16x32_bf16(wf, bfr[ks], acc, 0, 0, 0);
    }
    int d0 = ct * 16 + g * 4;
    int ob = otok * 128 + d0;
    float4 sk = *(const float4*)(skip + ob);
    float4 b4 = *(const float4*)(bpr + d0);
    float4 zv;
    zv.x = acc[0] + b4.x + sk.x;
    zv.y = acc[1] + b4.y + sk.y;
    zv.z = acc[2] + b4.z + sk.z;
    zv.w = acc[3] + b4.w + sk.w;
    *(float4*)(out + ob) = zv;
  }
}

// ---------------------------------------------------------------------------
extern "C" void kernel_launch(void* const* d_in, const int* in_sizes, int n_in,
                              void* d_out, int out_size, void* d_ws, size_t ws_size,
                              hipStream_t stream)
{
  (void)in_sizes; (void)n_in; (void)out_size; (void)ws_size;
  const float* q    = (const float*)d_in[0];
  const float* k    = (const float*)d_in[1];
  const float* v    = (const float*)d_in[2];
  const float* skip = (const float*)d_in[3];
  const float* temp = (const float*)d_in[4];
  const float* gq   = (const float*)d_in[5];
  const float* bq_l = (const float*)d_in[6];
  const float* gk   = (const float*)d_in[7];
  const float* bk_l = (const float*)d_in[8];
  const float* gv   = (const float*)d_in[9];
  const float* bv_l = (const float*)d_in[10];
  const float* wq   = (const float*)d_in[11];
  const float* bq   = (const float*)d_in[12];
  const float* wk   = (const float*)d_in[13];
  const float* bk   = (const float*)d_in[14];
  const float* wv   = (const float*)d_in[15];
  const float* bv   = (const float*)d_in[16];
  const float* wp   = (const float*)d_in[17];
  const float* bp   = (const float*)d_in[18];
  float* out = (float*)d_out;

  const size_t S = (size_t)2 * 256 * 256 * 128;   // 16,777,216 elements per tensor
  u16* Qp  = (u16*)d_ws;
  u16* Kp  = Qp + S;
  u16* VpT = Kp + S;

  ln_proj_mfma<<<dim3(256, 3), 256, 0, stream>>>(
      q, k, v, gq, bq_l, gk, bk_l, gv, bv_l,
      wq, bq, wk, bk, wv, bv, Qp, Kp, VpT);
  attn_mfma<<<dim3(2048), 256, 0, stream>>>(Qp, Kp, VpT, temp);
  out_proj_mfma<<<dim3(512), 256, 0, stream>>>(Qp, wp, bp, skip, out);
}

// Round 6
// 331.785 us; speedup vs baseline: 1.1351x; 1.0514x over previous
//
#include <hip/hip_runtime.h>

// CrossWinAttention MI355X — round 6.
// New: K0a/K0b setup kernels precompute S, B2 and pre-swizzled bf16 weight LDS-images
// into ws tail; K1/K3 stage weights via linear conflict-free int4 copy. K1 shrunk to
// 1 tile/block (grid 2048x3) to cut VGPR and raise occupancy. f2bf via native __bf16
// cast (hardware cvt, ~5x fewer VALU ops than manual RNE). K2 logic unchanged.
// Fallback (ws too small): in-kernel weight build, conflict-free mapping.

typedef unsigned short u16;
typedef unsigned int u32;
typedef short bf16x8 __attribute__((ext_vector_type(8)));
typedef float f32x4 __attribute__((ext_vector_type(4)));

__device__ __forceinline__ float bf2f(u16 u) {
  union { unsigned int i; float f; } v; v.i = ((unsigned int)u) << 16; return v.f;
}
__device__ __forceinline__ u16 f2bf(float f) {
  __bf16 h = (__bf16)f;          // native RNE convert (v_cvt_pk_bf16_f32 pairs)
  u16 r; __builtin_memcpy(&r, &h, 2); return r;
}

#define IMG_ELEMS (128 * 136)   // u16 elements per weight image (pad 136, swizzled)

// ---------------------------------------------------------------------------
// K0a: S_c = sum_d g_d W[d][c]; B2_c = bias_c + sum_d b_d W[d][c].  grid(3),256.
// ---------------------------------------------------------------------------
__global__ __launch_bounds__(256) void setup_sb(
    const float* __restrict__ g_q, const float* __restrict__ b_q,
    const float* __restrict__ g_k, const float* __restrict__ b_k,
    const float* __restrict__ g_v, const float* __restrict__ b_v,
    const float* __restrict__ wq, const float* __restrict__ bq,
    const float* __restrict__ wk, const float* __restrict__ bk,
    const float* __restrict__ wv, const float* __restrict__ bv,
    float* __restrict__ Sg, float* __restrict__ B2g)
{
  const float *gp, *bp, *Wp, *biasp;
  int y = blockIdx.x;
  if (y == 0)      { gp = g_q; bp = b_q; Wp = wq; biasp = bq; }
  else if (y == 1) { gp = g_k; bp = b_k; Wp = wk; biasp = bk; }
  else             { gp = g_v; bp = b_v; Wp = wv; biasp = bv; }
  int c = threadIdx.x & 127;
  float acc = 0.f;
#pragma unroll 8
  for (int d = 0; d < 128; ++d) {
    float coef = (threadIdx.x < 128) ? gp[d] : bp[d];
    acc += coef * Wp[d * 128 + c];
  }
  if (threadIdx.x < 128) Sg[y * 128 + c] = acc;
  else                   B2g[y * 128 + c] = acc + biasp[c];
}

// ---------------------------------------------------------------------------
// K0b: build swizzled bf16 weight images: img[c*136 + (d ^ ((c&15)<<3))] = w[d][c]*m_d.
// y=0..2: g-folded projections; y=3: 0.25-folded out-proj. grid(8,4), 256.
// ---------------------------------------------------------------------------
__global__ __launch_bounds__(256) void setup_w(
    const float* __restrict__ g_q, const float* __restrict__ g_k, const float* __restrict__ g_v,
    const float* __restrict__ wq, const float* __restrict__ wk, const float* __restrict__ wv,
    const float* __restrict__ wp, u16* __restrict__ imgs)
{
  int y = blockIdx.y;
  const float* Wp; const float* gp = nullptr; float mul = 1.f;
  if (y == 0)      { Wp = wq; gp = g_q; }
  else if (y == 1) { Wp = wk; gp = g_k; }
  else if (y == 2) { Wp = wv; gp = g_v; }
  else             { Wp = wp; mul = 0.25f; }
  u16* img = imgs + y * IMG_ELEMS;
#pragma unroll
  for (int it = 0; it < 4; ++it) {
    int f = (blockIdx.x * 4 + it) * 256 + threadIdx.x;   // u32-chunk id, 0..8191
    int c = f & 127, d0 = (f >> 7) * 2;
    float m0 = gp ? gp[d0] : mul, m1 = gp ? gp[d0 + 1] : mul;
    float w0 = Wp[d0 * 128 + c] * m0;
    float w1 = Wp[(d0 + 1) * 128 + c] * m1;
    u32 pk = (u32)f2bf(w0) | ((u32)f2bf(w1) << 16);
    *(u32*)&img[c * 136 + (d0 ^ ((c & 15) << 3))] = pk;
  }
}

// ---------------------------------------------------------------------------
// K1: LN folded into bf16 MFMA projection. grid (2048, 3): 1 tile (64 tok)/block.
// Weights staged by linear int4 copy of precomputed image (17 loads/thread).
// ---------------------------------------------------------------------------
__global__ __launch_bounds__(256) void ln_proj_mfma(
    const float* __restrict__ xq, const float* __restrict__ xk, const float* __restrict__ xv,
    const float* __restrict__ g_q, const float* __restrict__ b_q,
    const float* __restrict__ g_k, const float* __restrict__ b_k,
    const float* __restrict__ g_v, const float* __restrict__ b_v,
    const float* __restrict__ wq, const float* __restrict__ bq,
    const float* __restrict__ wk, const float* __restrict__ bk,
    const float* __restrict__ wv, const float* __restrict__ bv,
    const u16* __restrict__ imgs, const float* __restrict__ Sg, const float* __restrict__ B2g,
    u16* __restrict__ Qp, u16* __restrict__ Kp, u16* __restrict__ VpT)
{
  __shared__ u16   Wt_s[IMG_ELEMS];   // 34 KB
  __shared__ float S_s[128], B2_s[128];

  const int y = blockIdx.y, tid = threadIdx.x;
  const float *xp, *gp, *bp, *Wp, *biasp;
  u16* outp;
  if (y == 0)      { xp = xq; gp = g_q; bp = b_q; Wp = wq; biasp = bq; outp = Qp; }
  else if (y == 1) { xp = xk; gp = g_k; bp = b_k; Wp = wk; biasp = bk; outp = Kp; }
  else             { xp = xv; gp = g_v; bp = b_v; Wp = wv; biasp = bv; outp = VpT; }

  if (imgs) {
    // ---- fast path: linear conflict-free copy of precomputed image ----
    const int4* src = (const int4*)(imgs + y * IMG_ELEMS);
    int4* dst = (int4*)Wt_s;
#pragma unroll
    for (int i = 0; i < 17; ++i) dst[i * 256 + tid] = src[i * 256 + tid];   // 4352 int4
    if (tid < 128) S_s[tid] = Sg[y * 128 + tid];
    else           B2_s[tid - 128] = B2g[y * 128 + (tid - 128)];
  } else {
    // ---- fallback: build in-block, conflict-free mapping ----
    for (int it = 0; it < 32; ++it) {
      int c = it * 4 + (tid >> 6), d0 = (tid & 63) * 2;
      float w0 = Wp[d0 * 128 + c] * gp[d0];
      float w1 = Wp[(d0 + 1) * 128 + c] * gp[d0 + 1];
      u32 pk = (u32)f2bf(w0) | ((u32)f2bf(w1) << 16);
      *(u32*)&Wt_s[c * 136 + (d0 ^ ((c & 15) << 3))] = pk;
    }
    int c = tid & 127;
    float accv = 0.f;
#pragma unroll 4
    for (int d = 0; d < 128; ++d) {
      float coef = (tid < 128) ? gp[d] : bp[d];
      accv += coef * Wp[d * 128 + c];
    }
    if (tid < 128) S_s[c] = accv;
    else           B2_s[c] = accv + biasp[c];
  }
  __syncthreads();

  const int lane = tid & 63, wv_ = tid >> 6;
  const int c0 = lane & 15, g = lane >> 4;

  // ---- one 64-token tile: wave strip = 16 tokens ----
  const int tok = blockIdx.x * 64 + wv_ * 16 + c0;
  const int tt = tok & 255, bl = tok >> 8;
  const int l = bl & 255, bi = bl >> 8;
  const int xx = l >> 4, yy = l & 15;
  const int n = tt >> 6, w1_ = (tt >> 3) & 7, w2 = tt & 7;
  const int row = (((((bi * 4 + n) * 16 + xx) * 16 + yy) * 8 + w1_) * 8 + w2) * 128;

  float s1 = 0.f, s2 = 0.f;
  bf16x8 xf[4];
#pragma unroll
  for (int ks = 0; ks < 4; ++ks) {
    float4 lo = *(const float4*)(xp + row + ks * 32 + g * 8);
    float4 hi = *(const float4*)(xp + row + ks * 32 + g * 8 + 4);
    s1 += lo.x + lo.y + lo.z + lo.w + hi.x + hi.y + hi.z + hi.w;
    s2 += lo.x * lo.x + lo.y * lo.y + lo.z * lo.z + lo.w * lo.w
        + hi.x * hi.x + hi.y * hi.y + hi.z * hi.z + hi.w * hi.w;
    bf16x8 xv;
    xv[0] = (short)f2bf(lo.x); xv[1] = (short)f2bf(lo.y);
    xv[2] = (short)f2bf(lo.z); xv[3] = (short)f2bf(lo.w);
    xv[4] = (short)f2bf(hi.x); xv[5] = (short)f2bf(hi.y);
    xv[6] = (short)f2bf(hi.z); xv[7] = (short)f2bf(hi.w);
    xf[ks] = xv;
  }
  s1 += __shfl_xor(s1, 16); s2 += __shfl_xor(s2, 16);
  s1 += __shfl_xor(s1, 32); s2 += __shfl_xor(s2, 32);
  const float mu = s1 * (1.0f / 128.0f);
  const float var = s2 * (1.0f / 128.0f) - mu * mu;
  const float rs = rsqrtf(var + 1e-5f);

#pragma unroll
  for (int ct = 0; ct < 8; ++ct) {
    const int cb = ct * 16 + g * 4;
    f32x4 acc = {0.f, 0.f, 0.f, 0.f};
#pragma unroll
    for (int ks = 0; ks < 4; ++ks) {
      bf16x8 wf = *(const bf16x8*)&Wt_s[(ct * 16 + c0) * 136 + ((ks * 32 + g * 8) ^ (c0 << 3))];
      acc = __builtin_amdgcn_mfma_f32_16x16x32_bf16(wf, xf[ks], acc, 0, 0, 0);
    }
    float4 S4 = *(const float4*)&S_s[cb];
    float4 B4 = *(const float4*)&B2_s[cb];
    float z0 = rs * (acc[0] - mu * S4.x) + B4.x;
    float z1 = rs * (acc[1] - mu * S4.y) + B4.y;
    float z2 = rs * (acc[2] - mu * S4.z) + B4.z;
    float z3 = rs * (acc[3] - mu * S4.w) + B4.w;
    if (y == 2) {
      // V stored transposed: [head][dh][t], head = (tok>>8)*4 + (cb>>5)
      int head = (tok >> 8) * 4 + (cb >> 5);
      int dh0 = cb & 31, tcol = tok & 255;
      outp[(head * 32 + dh0 + 0) * 256 + tcol] = f2bf(z0);
      outp[(head * 32 + dh0 + 1) * 256 + tcol] = f2bf(z1);
      outp[(head * 32 + dh0 + 2) * 256 + tcol] = f2bf(z2);
      outp[(head * 32 + dh0 + 3) * 256 + tcol] = f2bf(z3);
    } else {
      ushort4 zv;
      zv.x = f2bf(z0); zv.y = f2bf(z1); zv.z = f2bf(z2); zv.w = f2bf(z3);
      *(ushort4*)(outp + tok * 128 + cb) = zv;
    }
  }
}

// ---------------------------------------------------------------------------
// K2: attention per (b,m,l). 2048 blocks x 256 thr. (Unchanged from verified round-5.)
// ---------------------------------------------------------------------------
__global__ __launch_bounds__(256) void attn_mfma(
    u16* __restrict__ Qp, const u16* __restrict__ Kp, const u16* __restrict__ VpT,
    const float* __restrict__ temperature)
{
  __shared__ u16 K_s[256 * 32];
  __shared__ u16 Vt_s[32 * 256];
  __shared__ u16 P_s[4][16 * 64];

  const int tid = threadIdx.x;
  const int bid = blockIdx.x;
  const int l = bid & 255, m = (bid >> 8) & 3, b = bid >> 10;
  const float scale = 0.17677669529663689f / temperature[b];
  const int base = (b * 256 + l) * 32768 + m * 32;
  const int head = (b * 256 + l) * 4 + m;

#pragma unroll
  for (int r = 0; r < 8; ++r) {
    int f = r * 256 + tid, t = f >> 3, c4 = (f & 7) * 4;
    *(ushort4*)&K_s[t * 32 + c4] = *(const ushort4*)(Kp + base + t * 128 + c4);
  }
#pragma unroll
  for (int r = 0; r < 8; ++r) {
    int f = r * 256 + tid, dh = f >> 6, c4 = (f & 63) * 4;
    ushort4 vv = *(const ushort4*)(VpT + (head * 32 + dh) * 256 + c4);
    *(ushort4*)&Vt_s[dh * 256 + (c4 ^ ((dh & 7) << 3))] = vv;
  }
  __syncthreads();

  const int lane = tid & 63, wv_ = tid >> 6;
  const int c0 = lane & 15, g = lane >> 4;
  u16* Pw = P_s[wv_];
  const f32x4 zero = {0.f, 0.f, 0.f, 0.f};

  for (int si = 0; si < 4; ++si) {
    const int qs = wv_ * 4 + si;
    bf16x8 qf = *(const bf16x8*)(Qp + base + (qs * 16 + c0) * 128 + g * 8);
    float p0 = 0.f, p1 = 0.f, p2 = 0.f, p3 = 0.f;
    f32x4 o0 = zero, o1 = zero;
    const int r0 = g * 4;
#pragma unroll 1
    for (int cc = 0; cc < 4; ++cc) {
      f32x4 s[4];
#pragma unroll
      for (int kt = 0; kt < 4; ++kt) {
        bf16x8 kf = *(const bf16x8*)&K_s[((cc * 4 + kt) * 16 + c0) * 32 + g * 8];
        s[kt] = __builtin_amdgcn_mfma_f32_16x16x32_bf16(qf, kf, zero, 0, 0, 0);
      }
#pragma unroll
      for (int kt = 0; kt < 4; ++kt) {
        float e0 = __expf(s[kt][0] * scale);
        float e1 = __expf(s[kt][1] * scale);
        float e2 = __expf(s[kt][2] * scale);
        float e3 = __expf(s[kt][3] * scale);
        p0 += e0; p1 += e1; p2 += e2; p3 += e3;
        int col = kt * 16 + c0;
        Pw[(r0 + 0) * 64 + (col ^ (((r0 + 0) & 7) << 3))] = f2bf(e0);
        Pw[(r0 + 1) * 64 + (col ^ (((r0 + 1) & 7) << 3))] = f2bf(e1);
        Pw[(r0 + 2) * 64 + (col ^ (((r0 + 2) & 7) << 3))] = f2bf(e2);
        Pw[(r0 + 3) * 64 + (col ^ (((r0 + 3) & 7) << 3))] = f2bf(e3);
      }
#pragma unroll
      for (int kc = 0; kc < 2; ++kc) {
        bf16x8 af = *(const bf16x8*)&Pw[c0 * 64 + ((kc * 32 + g * 8) ^ ((c0 & 7) << 3))];
        int Kg = cc * 64 + kc * 32 + g * 8;
        bf16x8 v0 = *(const bf16x8*)&Vt_s[c0 * 256 + (Kg ^ ((c0 & 7) << 3))];
        bf16x8 v1 = *(const bf16x8*)&Vt_s[(16 + c0) * 256 + (Kg ^ ((c0 & 7) << 3))];
        o0 = __builtin_amdgcn_mfma_f32_16x16x32_bf16(af, v0, o0, 0, 0, 0);
        o1 = __builtin_amdgcn_mfma_f32_16x16x32_bf16(af, v1, o1, 0, 0, 0);
      }
    }
#pragma unroll
    for (int off = 1; off <= 8; off <<= 1) {
      p0 += __shfl_xor(p0, off);
      p1 += __shfl_xor(p1, off);
      p2 += __shfl_xor(p2, off);
      p3 += __shfl_xor(p3, off);
    }
    float inv0 = 1.0f / p0, inv1 = 1.0f / p1, inv2 = 1.0f / p2, inv3 = 1.0f / p3;
    int qrow = qs * 16 + g * 4;
    Qp[base + (qrow + 0) * 128 + c0]      = f2bf(o0[0] * inv0);
    Qp[base + (qrow + 1) * 128 + c0]      = f2bf(o0[1] * inv1);
    Qp[base + (qrow + 2) * 128 + c0]      = f2bf(o0[2] * inv2);
    Qp[base + (qrow + 3) * 128 + c0]      = f2bf(o0[3] * inv3);
    Qp[base + (qrow + 0) * 128 + 16 + c0] = f2bf(o1[0] * inv0);
    Qp[base + (qrow + 1) * 128 + 16 + c0] = f2bf(o1[1] * inv1);
    Qp[base + (qrow + 2) * 128 + 16 + c0] = f2bf(o1[2] * inv2);
    Qp[base + (qrow + 3) * 128 + 16 + c0] = f2bf(o1[3] * inv3);
  }
}

// ---------------------------------------------------------------------------
// K3: out projection (MFMA) + mean over n + bias + skip. 512 blocks.
// ---------------------------------------------------------------------------
__global__ __launch_bounds__(256) void out_proj_mfma(
    const u16* __restrict__ Ap, const u16* __restrict__ img3,
    const float* __restrict__ wp, const float* __restrict__ bpr,
    const float* __restrict__ skip, float* __restrict__ out)
{
  __shared__ u16 WpT_s[IMG_ELEMS];
  const int tid = threadIdx.x;
  if (img3) {
    const int4* src = (const int4*)img3;
    int4* dst = (int4*)WpT_s;
#pragma unroll
    for (int i = 0; i < 17; ++i) dst[i * 256 + tid] = src[i * 256 + tid];
  } else {
    for (int it = 0; it < 32; ++it) {
      int c = it * 4 + (tid >> 6), d0 = (tid & 63) * 2;
      float w0 = wp[d0 * 128 + c] * 0.25f;
      float w1 = wp[(d0 + 1) * 128 + c] * 0.25f;
      u32 pk = (u32)f2bf(w0) | ((u32)f2bf(w1) << 16);
      *(u32*)&WpT_s[c * 136 + (d0 ^ ((c & 15) << 3))] = pk;
    }
  }
  __syncthreads();

  const int lane = tid & 63, wv_ = tid >> 6;
  const int c0 = lane & 15, g = lane >> 4;
  const int bl = blockIdx.x;
  const int w = wv_ * 16 + c0;
  const int otok = bl * 64 + w;

  bf16x8 bfr[4];
#pragma unroll
  for (int ks = 0; ks < 4; ++ks) {
    float acc8[8] = {0.f, 0.f, 0.f, 0.f, 0.f, 0.f, 0.f, 0.f};
#pragma unroll
    for (int n = 0; n < 4; ++n) {
      bf16x8 a = *(const bf16x8*)(Ap + (bl * 256 + n * 64 + w) * 128 + ks * 32 + g * 8);
#pragma unroll
      for (int e = 0; e < 8; ++e) acc8[e] += bf2f((u16)a[e]);
    }
    bf16x8 r;
#pragma unroll
    for (int e = 0; e < 8; ++e) r[e] = (short)f2bf(acc8[e]);
    bfr[ks] = r;
  }
#pragma unroll
  for (int ct = 0; ct < 8; ++ct) {
    f32x4 acc = {0.f, 0.f, 0.f, 0.f};
#pragma unroll
    for (int ks = 0; ks < 4; ++ks) {
      bf16x8 wf = *(const bf16x8*)&WpT_s[(ct * 16 + c0) * 136 + ((ks * 32 + g * 8) ^ (c0 << 3))];
      acc = __builtin_amdgcn_mfma_f32_16x16x32_bf16(wf, bfr[ks], acc, 0, 0, 0);
    }
    int d0 = ct * 16 + g * 4;
    int ob = otok * 128 + d0;
    float4 sk = *(const float4*)(skip + ob);
    float4 b4 = *(const float4*)(bpr + d0);
    float4 zv;
    zv.x = acc[0] + b4.x + sk.x;
    zv.y = acc[1] + b4.y + sk.y;
    zv.z = acc[2] + b4.z + sk.z;
    zv.w = acc[3] + b4.w + sk.w;
    *(float4*)(out + ob) = zv;
  }
}

// ---------------------------------------------------------------------------
extern "C" void kernel_launch(void* const* d_in, const int* in_sizes, int n_in,
                              void* d_out, int out_size, void* d_ws, size_t ws_size,
                              hipStream_t stream)
{
  (void)in_sizes; (void)n_in; (void)out_size;
  const float* q    = (const float*)d_in[0];
  const float* k    = (const float*)d_in[1];
  const float* v    = (const float*)d_in[2];
  const float* skip = (const float*)d_in[3];
  const float* temp = (const float*)d_in[4];
  const float* gq   = (const float*)d_in[5];
  const float* bq_l = (const float*)d_in[6];
  const float* gk   = (const float*)d_in[7];
  const float* bk_l = (const float*)d_in[8];
  const float* gv   = (const float*)d_in[9];
  const float* bv_l = (const float*)d_in[10];
  const float* wq   = (const float*)d_in[11];
  const float* bq   = (const float*)d_in[12];
  const float* wk   = (const float*)d_in[13];
  const float* bk   = (const float*)d_in[14];
  const float* wv   = (const float*)d_in[15];
  const float* bv   = (const float*)d_in[16];
  const float* wp   = (const float*)d_in[17];
  const float* bp   = (const float*)d_in[18];
  float* out = (float*)d_out;

  const size_t S = (size_t)2 * 256 * 256 * 128;   // 16,777,216 elems/tensor
  u16* Qp  = (u16*)d_ws;
  u16* Kp  = Qp + S;
  u16* VpT = Kp + S;
  u16* imgs = VpT + S;                            // 4 x IMG_ELEMS u16
  float* Sg  = (float*)(imgs + 4 * IMG_ELEMS);    // [3][128]
  float* B2g = Sg + 3 * 128;                      // [3][128]

  const size_t need = (size_t)3 * S * 2 + (size_t)4 * IMG_ELEMS * 2 + 6 * 128 * 4;
  const bool pre = (ws_size >= need);

  if (pre) {
    setup_sb<<<dim3(3), 256, 0, stream>>>(gq, bq_l, gk, bk_l, gv, bv_l,
                                          wq, bq, wk, bk, wv, bv, Sg, B2g);
    setup_w<<<dim3(8, 4), 256, 0, stream>>>(gq, gk, gv, wq, wk, wv, wp, imgs);
  }
  ln_proj_mfma<<<dim3(2048, 3), 256, 0, stream>>>(
      q, k, v, gq, bq_l, gk, bk_l, gv, bv_l,
      wq, bq, wk, bk, wv, bv,
      pre ? imgs : (const u16*)nullptr, Sg, B2g, Qp, Kp, VpT);
  attn_mfma<<<dim3(2048), 256, 0, stream>>>(Qp, Kp, VpT, temp);
  out_proj_mfma<<<dim3(512), 256, 0, stream>>>(
      Qp, pre ? (imgs + 3 * IMG_ELEMS) : (const u16*)nullptr, wp, bp, skip, out);
}